// Round 12
// baseline (86.692 us; speedup 1.0000x reference)
//
#include <hip/hip_runtime.h>

#define T 8192
#define BATCH 512
#define NTH 1024
#define EPT 8
#define NW 16

// Redundant per-wave scan of the 16 privatized 256-bin histograms at hb.
// Returns the selected bucket, count strictly above it, and its cumulative top.
__device__ __forceinline__ void radix_scan(const unsigned* hb, int lane, unsigned kk,
                                           unsigned& sel, unsigned& sub, unsigned& top) {
    unsigned bb = lane * 4;
    unsigned h0 = 0, h1 = 0, h2 = 0, h3 = 0;
#pragma unroll
    for (int w = 0; w < NW; w++) {
        const unsigned* p = hb + w * 256 + bb;
        h0 += p[0]; h1 += p[1]; h2 += p[2]; h3 += p[3];
    }
    unsigned s = h0 + h1 + h2 + h3;
    unsigned vs = s;
#pragma unroll
    for (int off = 1; off < 64; off <<= 1) {
        unsigned u = __shfl_down(vs, off);
        if (lane + off < 64) vs += u;
    }
    unsigned vnext = __shfl_down(vs, 1);
    if (lane == 63) vnext = 0u;
    unsigned higher = vs - s;
    unsigned S3 = higher + h3;
    unsigned S2 = S3 + h2;
    unsigned S1 = S2 + h1;
    unsigned S0 = S1 + h0;
    unsigned lsel = 0u, lsub = 0u, ltop = 0u;
    bool found = false;
    if (S3 >= kk && vnext < kk)    { lsel = bb + 3; lsub = vnext; ltop = S3; found = true; }
    else if (S2 >= kk && S3 < kk)  { lsel = bb + 2; lsub = S3;    ltop = S2; found = true; }
    else if (S1 >= kk && S2 < kk)  { lsel = bb + 1; lsub = S2;    ltop = S1; found = true; }
    else if (S0 >= kk && S1 < kk)  { lsel = bb + 0; lsub = S1;    ltop = S0; found = true; }
    unsigned long long ball = __ballot(found);
    int src = __ffsll(ball) - 1;
    sel = (unsigned)__shfl((int)lsel, src);
    sub = (unsigned)__shfl((int)lsub, src);
    top = (unsigned)__shfl((int)ltop, src);
}

__global__ __launch_bounds__(NTH) void teacher_kernel(
    const float* __restrict__ dur, const float* __restrict__ stats,
    const float* __restrict__ trace, const float* __restrict__ mask,
    const float* __restrict__ cue, float* __restrict__ out)
{
    const int row = blockIdx.x;
    const int tid = threadIdx.x;
    const int lane = tid & 63, wid = tid >> 6;

    __shared__ unsigned s_hist[2 * NW * 256];   // 32 KB ping-pong, per-wave copies
    __shared__ float s_red[NW * 13];
    __shared__ float s_vL[NW][EPT], s_vR[NW][EPT];
    __shared__ float s_part[EPT * NW];
    __shared__ unsigned s_wu[NW];

    const size_t BT = (size_t)BATCH * T;
    const size_t rbase = (size_t)row * T;
    const float* drow = dur + rbase;
    const float* mrow = mask + rbase;
    const float* crow = cue + rbase;
    const float4* trow = (const float4*)(trace + rbase * 4);

    float* o_spe = out + rbase;
    float* o_pae = out + BT + rbase;
    float* o_sb  = out + 2 * BT;
    float* o_pb  = out + 2 * BT + BATCH;
    float* o_al  = out + 2 * BT + 2 * BATCH + rbase;
    float* o_cf  = out + 3 * BT + 2 * BATCH;
    float4* o_tc = ((float4*)(out + 3 * BT + 3 * BATCH)) + rbase;
    float* o_pc  = out + 7 * BT + 3 * BATCH + rbase;
    float* o_bk  = out + 8 * BT + 3 * BATCH + rbase;

    float durr[EPT];

    // ---- Phase 1: full input read, 12 masked sums + stats max; clear own buf0 copy.
    // NO global stores in this phase.
    float statmax = (tid < BATCH) ? fminf(fmaxf(stats[tid * 5 + 4], 0.f), 1.f) : 0.f;
    float acc[12];
#pragma unroll
    for (int j = 0; j < 12; j++) acc[j] = 0.f;
#pragma unroll
    for (int i = 0; i < EPT; i++) {
        int t = i * NTH + tid;
        float m = mrow[t];
        float d = drow[t];
        float c = crow[t];
        float4 tr = trow[t];
        durr[i] = d;
        acc[0] += m;            acc[1] += d * m;
        acc[2] += tr.x * m;     acc[3] += tr.x * tr.x * m;
        acc[4] += tr.y * m;     acc[5] += tr.y * tr.y * m;
        acc[6] += tr.z * m;     acc[7] += tr.z * tr.z * m;
        acc[8] += tr.w * m;     acc[9] += tr.w * tr.w * m;
        acc[10] += c * m;       acc[11] += c * tr.z * m;
    }
    {   // clear this wave's buf0 histogram copy (wave-local)
        int hb = wid * 256 + lane * 4;
        s_hist[hb] = 0u; s_hist[hb + 1] = 0u; s_hist[hb + 2] = 0u; s_hist[hb + 3] = 0u;
    }
#pragma unroll
    for (int j = 0; j < 12; j++) {
        float x = acc[j];
#pragma unroll
        for (int off = 32; off; off >>= 1) x += __shfl_xor(x, off);
        if (lane == 0) s_red[wid * 13 + j] = x;
    }
    {
        float mx = statmax;
#pragma unroll
        for (int off = 32; off; off >>= 1) mx = fmaxf(mx, __shfl_xor(mx, off));
        if (lane == 0) s_red[wid * 13 + 12] = mx;
    }
    __syncthreads();                                   // B1
    float colv = 0.f;
    if (lane == 12) {
        colv = s_red[12];
#pragma unroll
        for (int w = 1; w < NW; w++) colv = fmaxf(colv, s_red[w * 13 + 12]);
    } else if (lane < 12) {
#pragma unroll
        for (int w = 0; w < NW; w++) colv += s_red[w * 13 + lane];
    }
    const float visible = fmaxf(__shfl(colv, 0), 1.f);
    const float sum_d   = __shfl(colv, 1);
    const float inv_vis = 1.f / visible;
    const float mean0 = __shfl(colv, 2) * inv_vis, ex20 = __shfl(colv, 3) * inv_vis;
    const float mean1 = __shfl(colv, 4) * inv_vis, ex21 = __shfl(colv, 5) * inv_vis;
    const float Sz    = __shfl(colv, 6);
    const float mean2 = Sz * inv_vis,              ex22 = __shfl(colv, 7) * inv_vis;
    const float mean3 = __shfl(colv, 8) * inv_vis, ex23 = __shfl(colv, 9) * inv_vis;
    const float n1    = __shfl(colv, 10);
    const float Scz   = __shfl(colv, 11);
    const float gmax  = __shfl(colv, 12);
    const float meanc = n1 * inv_vis;

    const float var1_raw = ex21 - mean1 * mean1;
    const float var2_raw = ex22 - mean2 * mean2;
    const float istd0 = 1.f / sqrtf(fmaxf(ex20 - mean0 * mean0, 1e-6f));
    const float istd1 = 1.f / sqrtf(fmaxf(var1_raw, 1e-6f));
    const float istd2 = 1.f / sqrtf(fmaxf(var2_raw, 1e-6f));
    const float istd3 = 1.f / sqrtf(fmaxf(ex23 - mean3 * mean3, 1e-6f));
    const float istdc = 1.f / sqrtf(fmaxf(meanc - meanc * meanc, 1e-6f));

    const int L = (int)(visible + 0.5f);

    const float st0 = stats[row * 5 + 0], st1 = stats[row * 5 + 1];
    const float st2 = stats[row * 5 + 2], st4 = stats[row * 5 + 4];

    const float src_total = fmaxf(sum_d, 1.f);
    const float src_mean = src_total * inv_vis;
    const float ref_ms = fmaxf(st2, 1.f);
    const float rate_scale = fminf(fmaxf(ref_ms / fmaxf(src_mean, 1.f), 0.55f), 1.95f);
    const float speech_budget = src_total * rate_scale;
    const float pause_ratio = fminf(fmaxf(st0, 0.f), 0.49f);
    const float boundary_ratio = fminf(fmaxf(st4, 0.f), 1.f);
    const float mean_pause = fmaxf(st1, 0.f);
    const float pfr = speech_budget * pause_ratio / fmaxf(1.f - pause_ratio, 0.2f);
    const float pfe = visible * boundary_ratio * mean_pause;
    float pause_budget = fmaxf(0.35f * pfr + 0.65f * pfe, 0.f);
    pause_budget = fminf(pause_budget, speech_budget * 0.8f);

    float conf = 0.2f + 0.3f * fminf(fmaxf(st0, 0.f), 1.f)
               + 0.25f * fminf(fmaxf(st4, 0.f), 1.f)
               + 0.2f * mean2
               + 0.1f * expf(-fmaxf(var1_raw, 0.f)) + 0.05f;
    conf = fminf(fmaxf(conf, 0.05f), 1.f);

    const float ratio = fminf(fmaxf(fmaxf(0.3f, gmax), 0.f), 1.f);
    int kint = (int)rintf(visible * ratio);
    kint = max(1, min(kint, L));

    // ---- Closed-form cosine gate (cue is 0/1)
    const float hi = fminf(fmaxf((1.f - meanc) * istdc, -1.5f), 1.5f);
    const float lo = fminf(fmaxf((0.f - meanc) * istdc, -1.5f), 1.5f);
    float pcoef;
    {
        float n0 = visible - n1;
        float sum_sp2 = hi * hi * n1 + lo * lo * n0;
        float sum_rb2 = istd2 * istd2 * visible * fmaxf(var2_raw, 0.f);
        float c1 = Scz - mean2 * n1;
        float c0 = (Sz - mean2 * visible) - c1;
        float dotv = istd2 * (hi * c1 + lo * c0);
        float xn = sqrtf(fmaxf(sum_sp2, 1e-6f));
        float yn = sqrtf(fmaxf(sum_rb2, 1e-6f));
        float agree = fminf(fmaxf(dotv / fmaxf(xn * yn, 1e-6f), -1.f), 1.f);
        float gate = 1.f / (1.f + expf(-(agree - 0.15f) * 4.f));
        pcoef = 0.35f * (0.05f + 0.5f * gate);
    }

    // ---- Phase 3: speech + pause scores (L3-hot reloads); NO global stores.
    float v[EPT], ps[EPT];
#pragma unroll
    for (int i = 0; i < EPT; i++) {
        int t = i * NTH + tid;
        float c = crow[t];
        float pf = (t == T - 1) ? 1.f : crow[t + 1];
        float4 tr = trow[t];
        float vv = 0.f, pp = 0.f;
        if (t < L) {
            float z1 = (tr.y - mean1) * istd1;
            float z3 = (tr.w - mean3) * istd3;
            vv = (1.f + fmaxf(durr[i], 0.f)) * expf(0.45f * z1 + 0.3f * z3 + 0.2f * pf);
            float z0 = (tr.x - mean0) * istd0;
            float rbv = (tr.z - mean2) * istd2;
            float spv = lo + c * (hi - lo);
            pp = expf(1.1f * z0 + 1.5f * rbv + pcoef * spv);
        }
        v[i] = vv; ps[i] = pp;
        if (lane == 0)  s_vL[wid][i] = vv;
        if (lane == 63) s_vR[wid][i] = vv;
    }
    // radix round-0 atomics into own buf0 copy (cleared in phase 1)
#pragma unroll
    for (int i = 0; i < EPT; i++)
        atomicAdd(&s_hist[wid * 256 + (__float_as_uint(ps[i]) >> 24)], 1u);
    __syncthreads();                                   // B2 (edges + round-0 hist)

    // ---- Region B2..B3: smooth3 + sum partial; round-0 scan; round-1 clear+atomics
    unsigned pref, kk = (unsigned)kint, cnt_eq = 0u;
    float a1 = 0.f;
#pragma unroll
    for (int i = 0; i < EPT; i++) {
        int t = i * NTH + tid;
        float vl = __shfl_up(v[i], 1);
        if (lane == 0)
            vl = (wid > 0) ? s_vR[wid - 1][i] : ((i > 0) ? s_vR[NW - 1][i - 1] : 0.f);
        float vr = __shfl_down(v[i], 1);
        if (lane == 63)
            vr = (wid < NW - 1) ? s_vL[wid + 1][i] : ((i + 1 < EPT) ? s_vL[0][i + 1] : 0.f);
        float smv = 0.f;
        if (t < L) smv = (vl + v[i] + vr) * (1.f / 3.f);
        v[i] = smv; a1 += smv;
    }
    {
#pragma unroll
        for (int off = 32; off; off >>= 1) a1 += __shfl_xor(a1, off);
        if (lane == 0) s_red[wid] = a1;
    }
    {
        unsigned sel, sub, top;
        radix_scan(s_hist, lane, kk, sel, sub, top);
        pref = sel << 24; kk -= sub;
    }
    {   // clear own buf1 copy, then round-1 atomics
        int hb = NW * 256 + wid * 256 + lane * 4;
        s_hist[hb] = 0u; s_hist[hb + 1] = 0u; s_hist[hb + 2] = 0u; s_hist[hb + 3] = 0u;
#pragma unroll
        for (int i = 0; i < EPT; i++) {
            unsigned b = __float_as_uint(ps[i]);
            if ((b & 0xFF000000u) == pref)
                atomicAdd(&s_hist[NW * 256 + wid * 256 + ((b >> 16) & 0xFFu)], 1u);
        }
    }
    __syncthreads();                                   // B3

    // ---- Region B3..B4: fold speech sum; round-1 scan; round-2 clear+atomics
    float tot1 = (lane < NW) ? s_red[lane] : 0.f;
#pragma unroll
    for (int off = 32; off; off >>= 1) tot1 += __shfl_xor(tot1, off);
    const float spe_scale = speech_budget / fmaxf(tot1, 1e-6f);
    {
        unsigned sel, sub, top;
        radix_scan(s_hist + NW * 256, lane, kk, sel, sub, top);
        pref |= sel << 16; kk -= sub;
    }
    {   // clear own buf0 copy, then round-2 atomics
        int hb = wid * 256 + lane * 4;
        s_hist[hb] = 0u; s_hist[hb + 1] = 0u; s_hist[hb + 2] = 0u; s_hist[hb + 3] = 0u;
#pragma unroll
        for (int i = 0; i < EPT; i++) {
            unsigned b = __float_as_uint(ps[i]);
            if ((b & 0xFFFF0000u) == pref)
                atomicAdd(&s_hist[wid * 256 + ((b >> 8) & 0xFFu)], 1u);
        }
    }
    __syncthreads();                                   // B4

    // ---- Region B4..B5: round-2 scan; round-3 clear+atomics
    {
        unsigned sel, sub, top;
        radix_scan(s_hist, lane, kk, sel, sub, top);
        pref |= sel << 8; kk -= sub;
    }
    {
        int hb = NW * 256 + wid * 256 + lane * 4;
        s_hist[hb] = 0u; s_hist[hb + 1] = 0u; s_hist[hb + 2] = 0u; s_hist[hb + 3] = 0u;
#pragma unroll
        for (int i = 0; i < EPT; i++) {
            unsigned b = __float_as_uint(ps[i]);
            if ((b & 0xFFFFFF00u) == pref)
                atomicAdd(&s_hist[NW * 256 + wid * 256 + (b & 0xFFu)], 1u);
        }
    }
    __syncthreads();                                   // B5

    // ---- Region B5..B6: round-3 scan; keep top-k; kept-sum partial
    {
        unsigned sel, sub, top;
        radix_scan(s_hist + NW * 256, lane, kk, sel, sub, top);
        pref |= sel; kk -= sub;
        cnt_eq = top - sub;
    }
    const unsigned thr_bits = pref;
    const unsigned keep_eq = kk;

    float accp = 0.f;
    if (cnt_eq == keep_eq) {
#pragma unroll
        for (int c = 0; c < EPT; c++) {
            unsigned b = __float_as_uint(ps[c]);
            float pv = (b >= thr_bits) ? ps[c] : 0.f;
            ps[c] = pv; accp += pv;
        }
    } else {
        unsigned carry_eq = 0u;
#pragma unroll
        for (int c = 0; c < EPT; c++) {
            unsigned b = __float_as_uint(ps[c]);
            bool eq = (b == thr_bits);
            unsigned long long bal = __ballot(eq);
            unsigned lpre = (unsigned)__popcll(bal & ((1ull << lane) - 1ull));
            unsigned wc = (unsigned)__popcll(bal);
            if (lane == 0) s_wu[wid] = wc;
            __syncthreads();
            unsigned woff = 0u, tot = 0u;
#pragma unroll
            for (int w = 0; w < NW; w++) { unsigned x = s_wu[w]; if (w < wid) woff += x; tot += x; }
            __syncthreads();
            unsigned rank = carry_eq + woff + lpre;
            bool keep = (b > thr_bits) || (eq && rank < keep_eq);
            float pv = keep ? ps[c] : 0.f;
            ps[c] = pv; accp += pv;
            carry_eq += tot;
        }
    }
    {
#pragma unroll
        for (int off = 32; off; off >>= 1) accp += __shfl_xor(accp, off);
        if (lane == 0) s_red[wid] = accp;
    }
    __syncthreads();                                   // B6

    // ---- Region B6..B7: fold kept sum; prefix-scan prep (NO global stores yet)
    float tot2 = (lane < NW) ? s_red[lane] : 0.f;
#pragma unroll
    for (int off = 32; off; off >>= 1) tot2 += __shfl_xor(tot2, off);
    const float pa_scale = pause_budget / fmaxf(tot2, 1e-6f);
    const float inv_alloc = 1.f / fmaxf(speech_budget + pause_budget, 1e-6f);
#pragma unroll
    for (int c = 0; c < EPT; c++) {
        int t = c * NTH + tid;
        bool in = t < L;
        float x = in ? (v[c] * spe_scale + ps[c] * pa_scale - durr[c]) : 0.f;
#pragma unroll
        for (int off = 1; off < 64; off <<= 1) {
            float u = __shfl_up(x, off);
            if (lane >= off) x += u;
        }
        durr[c] = x;                     // per-lane inclusive scan within wave
        if (lane == 63) s_part[c * NW + wid] = x;
    }
    __syncthreads();                                   // B7 (last barrier)

    // ---- Final: redundant 128-partial scan, then ALL global stores (no barrier after)
    {
        float a = s_part[2 * lane], b = s_part[2 * lane + 1];
        float pair = a + b;
        float inc = pair;
#pragma unroll
        for (int off = 1; off < 64; off <<= 1) {
            float u = __shfl_up(inc, off);
            if (lane >= off) inc += u;
        }
        float excl = inc - pair;
#pragma unroll
        for (int c = 0; c < EPT; c++) {
            int t = c * NTH + tid;
            bool in = t < L;
            float4 tr = trow[t];         // L3-hot reload for trace_ctx
            float m = in ? 1.f : 0.f;
            float spe = v[c] * spe_scale;
            float pae = ps[c] * pa_scale;
            int p = c * NW + wid;
            float e  = __shfl(excl, p >> 1);
            float av = __shfl(a,    p >> 1);
            float off0 = e + ((p & 1) ? av : 0.f);
            float incl = off0 + durr[c];
            o_spe[t] = spe;
            o_pae[t] = pae;
            o_al[t] = (spe + pae) * inv_alloc;
            o_tc[t] = make_float4(tr.x * m, tr.y * m, tr.z * m, tr.w * m);
            o_pc[t] = in ? incl : 0.f;
            o_bk[t] = in ? fmaxf(incl, 0.f) : 0.f;
        }
    }

    if (tid == 0) {
        o_sb[row] = speech_budget;
        o_pb[row] = pause_budget;
        o_cf[row] = conf;
    }
}

extern "C" void kernel_launch(void* const* d_in, const int* in_sizes, int n_in,
                              void* d_out, int out_size, void* d_ws, size_t ws_size,
                              hipStream_t stream) {
    const float* dur   = (const float*)d_in[0];
    const float* stats = (const float*)d_in[1];
    const float* trace = (const float*)d_in[2];
    const float* mask  = (const float*)d_in[3];
    const float* cue   = (const float*)d_in[4];
    float* out = (float*)d_out;

    teacher_kernel<<<dim3(BATCH), dim3(NTH), 0, stream>>>(dur, stats, trace, mask, cue, out);
}

// Round 13
// 80.273 us; speedup vs baseline: 1.0800x; 1.0800x over previous
//
#include <hip/hip_runtime.h>

#define T 8192
#define BATCH 512
#define NTH 1024
#define EPT 8
#define NW 16

// Redundant per-wave scan of the 16 privatized 256-bin histograms at hb.
__device__ __forceinline__ void radix_scan(const unsigned* hb, int lane, unsigned kk,
                                           unsigned& sel, unsigned& sub, unsigned& top) {
    unsigned bb = lane * 4;
    unsigned h0 = 0, h1 = 0, h2 = 0, h3 = 0;
#pragma unroll
    for (int w = 0; w < NW; w++) {
        const unsigned* p = hb + w * 256 + bb;
        h0 += p[0]; h1 += p[1]; h2 += p[2]; h3 += p[3];
    }
    unsigned s = h0 + h1 + h2 + h3;
    unsigned vs = s;
#pragma unroll
    for (int off = 1; off < 64; off <<= 1) {
        unsigned u = __shfl_down(vs, off);
        if (lane + off < 64) vs += u;
    }
    unsigned vnext = __shfl_down(vs, 1);
    if (lane == 63) vnext = 0u;
    unsigned higher = vs - s;
    unsigned S3 = higher + h3;
    unsigned S2 = S3 + h2;
    unsigned S1 = S2 + h1;
    unsigned S0 = S1 + h0;
    unsigned lsel = 0u, lsub = 0u, ltop = 0u;
    bool found = false;
    if (S3 >= kk && vnext < kk)    { lsel = bb + 3; lsub = vnext; ltop = S3; found = true; }
    else if (S2 >= kk && S3 < kk)  { lsel = bb + 2; lsub = S3;    ltop = S2; found = true; }
    else if (S1 >= kk && S2 < kk)  { lsel = bb + 1; lsub = S2;    ltop = S1; found = true; }
    else if (S0 >= kk && S1 < kk)  { lsel = bb + 0; lsub = S1;    ltop = S0; found = true; }
    unsigned long long ball = __ballot(found);
    int src = __ffsll(ball) - 1;
    sel = (unsigned)__shfl((int)lsel, src);
    sub = (unsigned)__shfl((int)lsub, src);
    top = (unsigned)__shfl((int)ltop, src);
}

__global__ __launch_bounds__(NTH) void teacher_kernel(
    const float* __restrict__ dur, const float* __restrict__ stats,
    const float* __restrict__ trace, const float* __restrict__ mask,
    const float* __restrict__ cue, float* __restrict__ out)
{
    const int row = blockIdx.x;
    const int tid = threadIdx.x;
    const int lane = tid & 63, wid = tid >> 6;

    __shared__ unsigned s_hist[2 * NW * 256];   // 32 KB ping-pong, per-wave copies
    __shared__ float s_red[NW * 12];
    __shared__ float s_vL[NW][EPT], s_vR[NW][EPT];
    __shared__ float s_part[EPT * NW];
    __shared__ unsigned s_wu[NW];

    const size_t BT = (size_t)BATCH * T;
    const size_t rbase = (size_t)row * T;
    const float* drow = dur + rbase;
    const float* mrow = mask + rbase;
    const float* crow = cue + rbase;
    const float4* trow = (const float4*)(trace + rbase * 4);

    float* o_spe = out + rbase;
    float* o_pae = out + BT + rbase;
    float* o_sb  = out + 2 * BT;
    float* o_pb  = out + 2 * BT + BATCH;
    float* o_al  = out + 2 * BT + 2 * BATCH + rbase;
    float* o_cf  = out + 3 * BT + 2 * BATCH;
    float4* o_tc = ((float4*)(out + 3 * BT + 3 * BATCH)) + rbase;
    float* o_pc  = out + 7 * BT + 3 * BATCH + rbase;
    float* o_bk  = out + 8 * BT + 3 * BATCH + rbase;

    // ---- L via 3-probe 64-ary ballot search (mask is a prefix mask by construction;
    //      the reference's own top-k relies on this). Saves the 16 MB mask stream.
    int L;
    {
        float p1 = mrow[lane * 128];
        unsigned long long b1 = __ballot(p1 > 0.5f);
        int seg = __popcll(b1) - 1;          // L >= 1 always (lengths >= T/2)
        int bse = seg * 128;
        float p2 = mrow[bse + lane * 2];
        int c2 = __popcll(__ballot(p2 > 0.5f));
        float p3 = mrow[bse + 2 * c2 - 1];
        L = bse + 2 * c2 - 1 + ((p3 > 0.5f) ? 1 : 0);
    }
    const float visible = (float)L;
    const float inv_vis = 1.f / visible;

    float durr[EPT];

    // ---- Phase 1: read dur/cue/trace, 11 masked sums + stats max; clear own buf0 copy
    float statmax = (tid < BATCH) ? fminf(fmaxf(stats[tid * 5 + 4], 0.f), 1.f) : 0.f;
    float acc[11];
#pragma unroll
    for (int j = 0; j < 11; j++) acc[j] = 0.f;
#pragma unroll
    for (int i = 0; i < EPT; i++) {
        int t = i * NTH + tid;
        float m = (t < L) ? 1.f : 0.f;
        float d = drow[t];
        float c = crow[t];
        float4 tr = trow[t];
        durr[i] = d;
        acc[0] += d * m;
        acc[1] += tr.x * m;     acc[2] += tr.x * tr.x * m;
        acc[3] += tr.y * m;     acc[4] += tr.y * tr.y * m;
        acc[5] += tr.z * m;     acc[6] += tr.z * tr.z * m;
        acc[7] += tr.w * m;     acc[8] += tr.w * tr.w * m;
        acc[9] += c * m;        acc[10] += c * tr.z * m;
    }
    {   // clear this wave's buf0 histogram copy (wave-local)
        int hb = wid * 256 + lane * 4;
        s_hist[hb] = 0u; s_hist[hb + 1] = 0u; s_hist[hb + 2] = 0u; s_hist[hb + 3] = 0u;
    }
#pragma unroll
    for (int j = 0; j < 11; j++) {
        float x = acc[j];
#pragma unroll
        for (int off = 32; off; off >>= 1) x += __shfl_xor(x, off);
        if (lane == 0) s_red[wid * 12 + j] = x;
    }
    {
        float mx = statmax;
#pragma unroll
        for (int off = 32; off; off >>= 1) mx = fmaxf(mx, __shfl_xor(mx, off));
        if (lane == 0) s_red[wid * 12 + 11] = mx;
    }
    __syncthreads();                                   // B1
    float colv = 0.f;
    if (lane == 11) {
        colv = s_red[11];
#pragma unroll
        for (int w = 1; w < NW; w++) colv = fmaxf(colv, s_red[w * 12 + 11]);
    } else if (lane < 11) {
#pragma unroll
        for (int w = 0; w < NW; w++) colv += s_red[w * 12 + lane];
    }
    const float sum_d   = __shfl(colv, 0);
    const float mean0 = __shfl(colv, 1) * inv_vis, ex20 = __shfl(colv, 2) * inv_vis;
    const float mean1 = __shfl(colv, 3) * inv_vis, ex21 = __shfl(colv, 4) * inv_vis;
    const float Sz    = __shfl(colv, 5);
    const float mean2 = Sz * inv_vis,              ex22 = __shfl(colv, 6) * inv_vis;
    const float mean3 = __shfl(colv, 7) * inv_vis, ex23 = __shfl(colv, 8) * inv_vis;
    const float n1    = __shfl(colv, 9);
    const float Scz   = __shfl(colv, 10);
    const float gmax  = __shfl(colv, 11);
    const float meanc = n1 * inv_vis;

    const float var1_raw = ex21 - mean1 * mean1;
    const float var2_raw = ex22 - mean2 * mean2;
    const float istd0 = 1.f / sqrtf(fmaxf(ex20 - mean0 * mean0, 1e-6f));
    const float istd1 = 1.f / sqrtf(fmaxf(var1_raw, 1e-6f));
    const float istd2 = 1.f / sqrtf(fmaxf(var2_raw, 1e-6f));
    const float istd3 = 1.f / sqrtf(fmaxf(ex23 - mean3 * mean3, 1e-6f));
    const float istdc = 1.f / sqrtf(fmaxf(meanc - meanc * meanc, 1e-6f));

    const float st0 = stats[row * 5 + 0], st1 = stats[row * 5 + 1];
    const float st2 = stats[row * 5 + 2], st4 = stats[row * 5 + 4];

    const float src_total = fmaxf(sum_d, 1.f);
    const float src_mean = src_total * inv_vis;
    const float ref_ms = fmaxf(st2, 1.f);
    const float rate_scale = fminf(fmaxf(ref_ms / fmaxf(src_mean, 1.f), 0.55f), 1.95f);
    const float speech_budget = src_total * rate_scale;
    const float pause_ratio = fminf(fmaxf(st0, 0.f), 0.49f);
    const float boundary_ratio = fminf(fmaxf(st4, 0.f), 1.f);
    const float mean_pause = fmaxf(st1, 0.f);
    const float pfr = speech_budget * pause_ratio / fmaxf(1.f - pause_ratio, 0.2f);
    const float pfe = visible * boundary_ratio * mean_pause;
    float pause_budget = fmaxf(0.35f * pfr + 0.65f * pfe, 0.f);
    pause_budget = fminf(pause_budget, speech_budget * 0.8f);

    float conf = 0.2f + 0.3f * fminf(fmaxf(st0, 0.f), 1.f)
               + 0.25f * fminf(fmaxf(st4, 0.f), 1.f)
               + 0.2f * mean2
               + 0.1f * expf(-fmaxf(var1_raw, 0.f)) + 0.05f;
    conf = fminf(fmaxf(conf, 0.05f), 1.f);

    const float ratio = fminf(fmaxf(fmaxf(0.3f, gmax), 0.f), 1.f);
    int kint = (int)rintf(visible * ratio);
    kint = max(1, min(kint, L));

    // ---- Closed-form cosine gate (cue is 0/1)
    const float hi = fminf(fmaxf((1.f - meanc) * istdc, -1.5f), 1.5f);
    const float lo = fminf(fmaxf((0.f - meanc) * istdc, -1.5f), 1.5f);
    float pcoef;
    {
        float n0 = visible - n1;
        float sum_sp2 = hi * hi * n1 + lo * lo * n0;
        float sum_rb2 = istd2 * istd2 * visible * fmaxf(var2_raw, 0.f);
        float c1 = Scz - mean2 * n1;
        float c0 = (Sz - mean2 * visible) - c1;
        float dotv = istd2 * (hi * c1 + lo * c0);
        float xn = sqrtf(fmaxf(sum_sp2, 1e-6f));
        float yn = sqrtf(fmaxf(sum_rb2, 1e-6f));
        float agree = fminf(fmaxf(dotv / fmaxf(xn * yn, 1e-6f), -1.f), 1.f);
        float gate = 1.f / (1.f + expf(-(agree - 0.15f) * 4.f));
        pcoef = 0.35f * (0.05f + 0.5f * gate);
    }

    // ---- Phase 3: speech + pause scores (L3-hot reloads) + tc store (overlaps radix)
    float v[EPT], ps[EPT];
#pragma unroll
    for (int i = 0; i < EPT; i++) {
        int t = i * NTH + tid;
        float c = crow[t];
        float pf = (t == T - 1) ? 1.f : crow[t + 1];
        float4 tr = trow[t];
        float m = (t < L) ? 1.f : 0.f;
        o_tc[t] = make_float4(tr.x * m, tr.y * m, tr.z * m, tr.w * m);
        float vv = 0.f, pp = 0.f;
        if (t < L) {
            float z1 = (tr.y - mean1) * istd1;
            float z3 = (tr.w - mean3) * istd3;
            vv = (1.f + fmaxf(durr[i], 0.f)) * expf(0.45f * z1 + 0.3f * z3 + 0.2f * pf);
            float z0 = (tr.x - mean0) * istd0;
            float rbv = (tr.z - mean2) * istd2;
            float spv = lo + c * (hi - lo);
            pp = expf(1.1f * z0 + 1.5f * rbv + pcoef * spv);
        }
        v[i] = vv; ps[i] = pp;
        if (lane == 0)  s_vL[wid][i] = vv;
        if (lane == 63) s_vR[wid][i] = vv;
    }
    // radix round-0 atomics into own buf0 copy (cleared in phase 1)
#pragma unroll
    for (int i = 0; i < EPT; i++)
        atomicAdd(&s_hist[wid * 256 + (__float_as_uint(ps[i]) >> 24)], 1u);
    __syncthreads();                                   // B2

    // ---- Region B2..B3: smooth3 + sum partial; round-0 scan; round-1 clear+atomics
    unsigned pref, kk = (unsigned)kint, cnt_eq = 0u;
    float a1 = 0.f;
#pragma unroll
    for (int i = 0; i < EPT; i++) {
        int t = i * NTH + tid;
        float vl = __shfl_up(v[i], 1);
        if (lane == 0)
            vl = (wid > 0) ? s_vR[wid - 1][i] : ((i > 0) ? s_vR[NW - 1][i - 1] : 0.f);
        float vr = __shfl_down(v[i], 1);
        if (lane == 63)
            vr = (wid < NW - 1) ? s_vL[wid + 1][i] : ((i + 1 < EPT) ? s_vL[0][i + 1] : 0.f);
        float smv = 0.f;
        if (t < L) smv = (vl + v[i] + vr) * (1.f / 3.f);
        v[i] = smv; a1 += smv;
    }
    {
#pragma unroll
        for (int off = 32; off; off >>= 1) a1 += __shfl_xor(a1, off);
        if (lane == 0) s_red[wid] = a1;
    }
    {
        unsigned sel, sub, top;
        radix_scan(s_hist, lane, kk, sel, sub, top);
        pref = sel << 24; kk -= sub;
    }
    {
        int hb = NW * 256 + wid * 256 + lane * 4;
        s_hist[hb] = 0u; s_hist[hb + 1] = 0u; s_hist[hb + 2] = 0u; s_hist[hb + 3] = 0u;
#pragma unroll
        for (int i = 0; i < EPT; i++) {
            unsigned b = __float_as_uint(ps[i]);
            if ((b & 0xFF000000u) == pref)
                atomicAdd(&s_hist[NW * 256 + wid * 256 + ((b >> 16) & 0xFFu)], 1u);
        }
    }
    __syncthreads();                                   // B3

    // ---- Region B3..B4: fold speech sum; round-1 scan; round-2 clear+atomics
    float tot1 = (lane < NW) ? s_red[lane] : 0.f;
#pragma unroll
    for (int off = 32; off; off >>= 1) tot1 += __shfl_xor(tot1, off);
    const float spe_scale = speech_budget / fmaxf(tot1, 1e-6f);
    {
        unsigned sel, sub, top;
        radix_scan(s_hist + NW * 256, lane, kk, sel, sub, top);
        pref |= sel << 16; kk -= sub;
    }
    {
        int hb = wid * 256 + lane * 4;
        s_hist[hb] = 0u; s_hist[hb + 1] = 0u; s_hist[hb + 2] = 0u; s_hist[hb + 3] = 0u;
#pragma unroll
        for (int i = 0; i < EPT; i++) {
            unsigned b = __float_as_uint(ps[i]);
            if ((b & 0xFFFF0000u) == pref)
                atomicAdd(&s_hist[wid * 256 + ((b >> 8) & 0xFFu)], 1u);
        }
    }
    __syncthreads();                                   // B4

    // ---- Region B4..B5: round-2 scan; round-3 clear+atomics
    {
        unsigned sel, sub, top;
        radix_scan(s_hist, lane, kk, sel, sub, top);
        pref |= sel << 8; kk -= sub;
    }
    {
        int hb = NW * 256 + wid * 256 + lane * 4;
        s_hist[hb] = 0u; s_hist[hb + 1] = 0u; s_hist[hb + 2] = 0u; s_hist[hb + 3] = 0u;
#pragma unroll
        for (int i = 0; i < EPT; i++) {
            unsigned b = __float_as_uint(ps[i]);
            if ((b & 0xFFFFFF00u) == pref)
                atomicAdd(&s_hist[NW * 256 + wid * 256 + (b & 0xFFu)], 1u);
        }
    }
    __syncthreads();                                   // B5

    // ---- Region B5..B6: round-3 scan; keep top-k; kept-sum partial
    {
        unsigned sel, sub, top;
        radix_scan(s_hist + NW * 256, lane, kk, sel, sub, top);
        pref |= sel; kk -= sub;
        cnt_eq = top - sub;
    }
    const unsigned thr_bits = pref;
    const unsigned keep_eq = kk;

    float accp = 0.f;
    if (cnt_eq == keep_eq) {
#pragma unroll
        for (int c = 0; c < EPT; c++) {
            unsigned b = __float_as_uint(ps[c]);
            float pv = (b >= thr_bits) ? ps[c] : 0.f;
            ps[c] = pv; accp += pv;
        }
    } else {
        unsigned carry_eq = 0u;
#pragma unroll
        for (int c = 0; c < EPT; c++) {
            unsigned b = __float_as_uint(ps[c]);
            bool eq = (b == thr_bits);
            unsigned long long bal = __ballot(eq);
            unsigned lpre = (unsigned)__popcll(bal & ((1ull << lane) - 1ull));
            unsigned wc = (unsigned)__popcll(bal);
            if (lane == 0) s_wu[wid] = wc;
            __syncthreads();
            unsigned woff = 0u, tot = 0u;
#pragma unroll
            for (int w = 0; w < NW; w++) { unsigned x = s_wu[w]; if (w < wid) woff += x; tot += x; }
            __syncthreads();
            unsigned rank = carry_eq + woff + lpre;
            bool keep = (b > thr_bits) || (eq && rank < keep_eq);
            float pv = keep ? ps[c] : 0.f;
            ps[c] = pv; accp += pv;
            carry_eq += tot;
        }
    }
    {
#pragma unroll
        for (int off = 32; off; off >>= 1) accp += __shfl_xor(accp, off);
        if (lane == 0) s_red[wid] = accp;
    }
    __syncthreads();                                   // B6

    // ---- Region B6..B7: fold kept sum; prefix-scan prep
    float tot2 = (lane < NW) ? s_red[lane] : 0.f;
#pragma unroll
    for (int off = 32; off; off >>= 1) tot2 += __shfl_xor(tot2, off);
    const float pa_scale = pause_budget / fmaxf(tot2, 1e-6f);
    const float inv_alloc = 1.f / fmaxf(speech_budget + pause_budget, 1e-6f);
#pragma unroll
    for (int c = 0; c < EPT; c++) {
        int t = c * NTH + tid;
        bool in = t < L;
        float x = in ? (v[c] * spe_scale + ps[c] * pa_scale - durr[c]) : 0.f;
#pragma unroll
        for (int off = 1; off < 64; off <<= 1) {
            float u = __shfl_up(x, off);
            if (lane >= off) x += u;
        }
        durr[c] = x;
        if (lane == 63) s_part[c * NW + wid] = x;
    }
    __syncthreads();                                   // B7 (last barrier)

    // ---- Final: redundant 128-partial scan, then remaining stores (83 MB)
    {
        float a = s_part[2 * lane], b = s_part[2 * lane + 1];
        float pair = a + b;
        float inc = pair;
#pragma unroll
        for (int off = 1; off < 64; off <<= 1) {
            float u = __shfl_up(inc, off);
            if (lane >= off) inc += u;
        }
        float excl = inc - pair;
#pragma unroll
        for (int c = 0; c < EPT; c++) {
            int t = c * NTH + tid;
            bool in = t < L;
            float spe = v[c] * spe_scale;
            float pae = ps[c] * pa_scale;
            int p = c * NW + wid;
            float e  = __shfl(excl, p >> 1);
            float av = __shfl(a,    p >> 1);
            float off0 = e + ((p & 1) ? av : 0.f);
            float incl = off0 + durr[c];
            o_spe[t] = spe;
            o_pae[t] = pae;
            o_al[t] = (spe + pae) * inv_alloc;
            o_pc[t] = in ? incl : 0.f;
            o_bk[t] = in ? fmaxf(incl, 0.f) : 0.f;
        }
    }

    if (tid == 0) {
        o_sb[row] = speech_budget;
        o_pb[row] = pause_budget;
        o_cf[row] = conf;
    }
}

extern "C" void kernel_launch(void* const* d_in, const int* in_sizes, int n_in,
                              void* d_out, int out_size, void* d_ws, size_t ws_size,
                              hipStream_t stream) {
    const float* dur   = (const float*)d_in[0];
    const float* stats = (const float*)d_in[1];
    const float* trace = (const float*)d_in[2];
    const float* mask  = (const float*)d_in[3];
    const float* cue   = (const float*)d_in[4];
    float* out = (float*)d_out;

    teacher_kernel<<<dim3(BATCH), dim3(NTH), 0, stream>>>(dur, stats, trace, mask, cue, out);
}

// Round 14
// 75.436 us; speedup vs baseline: 1.1492x; 1.0641x over previous
//
#include <hip/hip_runtime.h>

#define T 8192
#define BATCH 512
#define NTH 1024
#define EPT 8
#define NW 16

// Redundant per-wave scan of the 16 privatized 256-bin histograms at hb.
__device__ __forceinline__ void radix_scan(const unsigned* hb, int lane, unsigned kk,
                                           unsigned& sel, unsigned& sub, unsigned& top) {
    unsigned bb = lane * 4;
    unsigned h0 = 0, h1 = 0, h2 = 0, h3 = 0;
#pragma unroll
    for (int w = 0; w < NW; w++) {
        const unsigned* p = hb + w * 256 + bb;
        h0 += p[0]; h1 += p[1]; h2 += p[2]; h3 += p[3];
    }
    unsigned s = h0 + h1 + h2 + h3;
    unsigned vs = s;
#pragma unroll
    for (int off = 1; off < 64; off <<= 1) {
        unsigned u = __shfl_down(vs, off);
        if (lane + off < 64) vs += u;
    }
    unsigned vnext = __shfl_down(vs, 1);
    if (lane == 63) vnext = 0u;
    unsigned higher = vs - s;
    unsigned S3 = higher + h3;
    unsigned S2 = S3 + h2;
    unsigned S1 = S2 + h1;
    unsigned S0 = S1 + h0;
    unsigned lsel = 0u, lsub = 0u, ltop = 0u;
    bool found = false;
    if (S3 >= kk && vnext < kk)    { lsel = bb + 3; lsub = vnext; ltop = S3; found = true; }
    else if (S2 >= kk && S3 < kk)  { lsel = bb + 2; lsub = S3;    ltop = S2; found = true; }
    else if (S1 >= kk && S2 < kk)  { lsel = bb + 1; lsub = S2;    ltop = S1; found = true; }
    else if (S0 >= kk && S1 < kk)  { lsel = bb + 0; lsub = S1;    ltop = S0; found = true; }
    unsigned long long ball = __ballot(found);
    int src = __ffsll(ball) - 1;
    sel = (unsigned)__shfl((int)lsel, src);
    sub = (unsigned)__shfl((int)lsub, src);
    top = (unsigned)__shfl((int)ltop, src);
}

__global__ __launch_bounds__(NTH) void teacher_kernel(
    const float* __restrict__ dur, const float* __restrict__ stats,
    const float* __restrict__ trace, const float* __restrict__ mask,
    const float* __restrict__ cue, float* __restrict__ out)
{
    const int row = blockIdx.x;
    const int tid = threadIdx.x;
    const int lane = tid & 63, wid = tid >> 6;

    __shared__ unsigned s_hist[2 * NW * 256];   // 32 KB ping-pong, per-wave copies
    __shared__ float s_red[NW * 12];
    __shared__ float s_vL[NW][EPT], s_vR[NW][EPT];
    __shared__ float s_part[EPT * NW];
    __shared__ unsigned s_wu[NW];

    const size_t BT = (size_t)BATCH * T;
    const size_t rbase = (size_t)row * T;
    const float* drow = dur + rbase;
    const float* mrow = mask + rbase;
    const float* crow = cue + rbase;
    const float4* trow = (const float4*)(trace + rbase * 4);

    float* o_spe = out + rbase;
    float* o_pae = out + BT + rbase;
    float* o_sb  = out + 2 * BT;
    float* o_pb  = out + 2 * BT + BATCH;
    float* o_al  = out + 2 * BT + 2 * BATCH + rbase;
    float* o_cf  = out + 3 * BT + 2 * BATCH;
    float4* o_tc = ((float4*)(out + 3 * BT + 3 * BATCH)) + rbase;
    float* o_pc  = out + 7 * BT + 3 * BATCH + rbase;
    float* o_bk  = out + 8 * BT + 3 * BATCH + rbase;

    // ---- L via 3-probe 64-ary ballot search (mask is a prefix mask by construction)
    int L;
    {
        float p1 = mrow[lane * 128];
        unsigned long long b1 = __ballot(p1 > 0.5f);
        int seg = __popcll(b1) - 1;
        int bse = seg * 128;
        float p2 = mrow[bse + lane * 2];
        int c2 = __popcll(__ballot(p2 > 0.5f));
        float p3 = mrow[bse + 2 * c2 - 1];
        L = bse + 2 * c2 - 1 + ((p3 > 0.5f) ? 1 : 0);
    }
    const float visible = (float)L;
    const float inv_vis = 1.f / visible;

    float durr[EPT];

    // ---- Phase 1: read dur/cue/trace, 11 masked sums + stats max; clear own buf0 copy
    float statmax = (tid < BATCH) ? fminf(fmaxf(stats[tid * 5 + 4], 0.f), 1.f) : 0.f;
    float acc[11];
#pragma unroll
    for (int j = 0; j < 11; j++) acc[j] = 0.f;
#pragma unroll
    for (int i = 0; i < EPT; i++) {
        int t = i * NTH + tid;
        float m = (t < L) ? 1.f : 0.f;
        float d = drow[t];
        float c = crow[t];
        float4 tr = trow[t];
        durr[i] = d;
        acc[0] += d * m;
        acc[1] += tr.x * m;     acc[2] += tr.x * tr.x * m;
        acc[3] += tr.y * m;     acc[4] += tr.y * tr.y * m;
        acc[5] += tr.z * m;     acc[6] += tr.z * tr.z * m;
        acc[7] += tr.w * m;     acc[8] += tr.w * tr.w * m;
        acc[9] += c * m;        acc[10] += c * tr.z * m;
    }
    {
        int hb = wid * 256 + lane * 4;
        s_hist[hb] = 0u; s_hist[hb + 1] = 0u; s_hist[hb + 2] = 0u; s_hist[hb + 3] = 0u;
    }
#pragma unroll
    for (int j = 0; j < 11; j++) {
        float x = acc[j];
#pragma unroll
        for (int off = 32; off; off >>= 1) x += __shfl_xor(x, off);
        if (lane == 0) s_red[wid * 12 + j] = x;
    }
    {
        float mx = statmax;
#pragma unroll
        for (int off = 32; off; off >>= 1) mx = fmaxf(mx, __shfl_xor(mx, off));
        if (lane == 0) s_red[wid * 12 + 11] = mx;
    }
    __syncthreads();                                   // B1
    float colv = 0.f;
    if (lane == 11) {
        colv = s_red[11];
#pragma unroll
        for (int w = 1; w < NW; w++) colv = fmaxf(colv, s_red[w * 12 + 11]);
    } else if (lane < 11) {
#pragma unroll
        for (int w = 0; w < NW; w++) colv += s_red[w * 12 + lane];
    }
    const float sum_d   = __shfl(colv, 0);
    const float mean0 = __shfl(colv, 1) * inv_vis, ex20 = __shfl(colv, 2) * inv_vis;
    const float mean1 = __shfl(colv, 3) * inv_vis, ex21 = __shfl(colv, 4) * inv_vis;
    const float Sz    = __shfl(colv, 5);
    const float mean2 = Sz * inv_vis,              ex22 = __shfl(colv, 6) * inv_vis;
    const float mean3 = __shfl(colv, 7) * inv_vis, ex23 = __shfl(colv, 8) * inv_vis;
    const float n1    = __shfl(colv, 9);
    const float Scz   = __shfl(colv, 10);
    const float gmax  = __shfl(colv, 11);
    const float meanc = n1 * inv_vis;

    const float var1_raw = ex21 - mean1 * mean1;
    const float var2_raw = ex22 - mean2 * mean2;
    const float istd0 = 1.f / sqrtf(fmaxf(ex20 - mean0 * mean0, 1e-6f));
    const float istd1 = 1.f / sqrtf(fmaxf(var1_raw, 1e-6f));
    const float istd2 = 1.f / sqrtf(fmaxf(var2_raw, 1e-6f));
    const float istd3 = 1.f / sqrtf(fmaxf(ex23 - mean3 * mean3, 1e-6f));
    const float istdc = 1.f / sqrtf(fmaxf(meanc - meanc * meanc, 1e-6f));

    const float st0 = stats[row * 5 + 0], st1 = stats[row * 5 + 1];
    const float st2 = stats[row * 5 + 2], st4 = stats[row * 5 + 4];

    const float src_total = fmaxf(sum_d, 1.f);
    const float src_mean = src_total * inv_vis;
    const float ref_ms = fmaxf(st2, 1.f);
    const float rate_scale = fminf(fmaxf(ref_ms / fmaxf(src_mean, 1.f), 0.55f), 1.95f);
    const float speech_budget = src_total * rate_scale;
    const float pause_ratio = fminf(fmaxf(st0, 0.f), 0.49f);
    const float boundary_ratio = fminf(fmaxf(st4, 0.f), 1.f);
    const float mean_pause = fmaxf(st1, 0.f);
    const float pfr = speech_budget * pause_ratio / fmaxf(1.f - pause_ratio, 0.2f);
    const float pfe = visible * boundary_ratio * mean_pause;
    float pause_budget = fmaxf(0.35f * pfr + 0.65f * pfe, 0.f);
    pause_budget = fminf(pause_budget, speech_budget * 0.8f);

    float conf = 0.2f + 0.3f * fminf(fmaxf(st0, 0.f), 1.f)
               + 0.25f * fminf(fmaxf(st4, 0.f), 1.f)
               + 0.2f * mean2
               + 0.1f * __expf(-fmaxf(var1_raw, 0.f)) + 0.05f;
    conf = fminf(fmaxf(conf, 0.05f), 1.f);

    const float ratio = fminf(fmaxf(fmaxf(0.3f, gmax), 0.f), 1.f);
    int kint = (int)rintf(visible * ratio);
    kint = max(1, min(kint, L));

    // ---- Closed-form cosine gate (cue is 0/1)
    const float hi = fminf(fmaxf((1.f - meanc) * istdc, -1.5f), 1.5f);
    const float lo = fminf(fmaxf((0.f - meanc) * istdc, -1.5f), 1.5f);
    float pchi, pclo;
    {
        float n0 = visible - n1;
        float sum_sp2 = hi * hi * n1 + lo * lo * n0;
        float sum_rb2 = istd2 * istd2 * visible * fmaxf(var2_raw, 0.f);
        float c1 = Scz - mean2 * n1;
        float c0 = (Sz - mean2 * visible) - c1;
        float dotv = istd2 * (hi * c1 + lo * c0);
        float xn = sqrtf(fmaxf(sum_sp2, 1e-6f));
        float yn = sqrtf(fmaxf(sum_rb2, 1e-6f));
        float agree = fminf(fmaxf(dotv / fmaxf(xn * yn, 1e-6f), -1.f), 1.f);
        float gate = 1.f / (1.f + __expf(-(agree - 0.15f) * 4.f));
        float pcoef = 0.35f * (0.05f + 0.5f * gate);
        pchi = pcoef * hi; pclo = pcoef * lo;
    }

    // ---- Phase 3: speech + pause scores (L3-hot reloads) + tc store (overlaps radix)
    float v[EPT], ps[EPT];
#pragma unroll
    for (int i = 0; i < EPT; i++) {
        int t = i * NTH + tid;
        float c = crow[t];
        float pf = (t == T - 1) ? 1.f : crow[t + 1];
        float4 tr = trow[t];
        float m = (t < L) ? 1.f : 0.f;
        o_tc[t] = make_float4(tr.x * m, tr.y * m, tr.z * m, tr.w * m);
        float vv = 0.f, pp = 0.f;
        if (t < L) {
            float z1 = (tr.y - mean1) * istd1;
            float z3 = (tr.w - mean3) * istd3;
            vv = (1.f + fmaxf(durr[i], 0.f)) * __expf(0.45f * z1 + 0.3f * z3 + 0.2f * pf);
            float z0 = (tr.x - mean0) * istd0;
            float rbv = (tr.z - mean2) * istd2;
            pp = __expf(1.1f * z0 + 1.5f * rbv + (c > 0.5f ? pchi : pclo));
        }
        v[i] = vv; ps[i] = pp;
        if (lane == 0)  s_vL[wid][i] = vv;
        if (lane == 63) s_vR[wid][i] = vv;
    }
    // radix round-0 atomics into own buf0 copy (cleared in phase 1)
#pragma unroll
    for (int i = 0; i < EPT; i++)
        atomicAdd(&s_hist[wid * 256 + (__float_as_uint(ps[i]) >> 24)], 1u);
    __syncthreads();                                   // B2

    // ---- Region B2..B3: smooth3 + sum partial; round-0 scan; round-1 clear+atomics
    unsigned pref, kk = (unsigned)kint, cnt_eq = 0u;
    float a1 = 0.f;
#pragma unroll
    for (int i = 0; i < EPT; i++) {
        int t = i * NTH + tid;
        float vl = __shfl_up(v[i], 1);
        if (lane == 0)
            vl = (wid > 0) ? s_vR[wid - 1][i] : ((i > 0) ? s_vR[NW - 1][i - 1] : 0.f);
        float vr = __shfl_down(v[i], 1);
        if (lane == 63)
            vr = (wid < NW - 1) ? s_vL[wid + 1][i] : ((i + 1 < EPT) ? s_vL[0][i + 1] : 0.f);
        float smv = 0.f;
        if (t < L) smv = (vl + v[i] + vr) * (1.f / 3.f);
        v[i] = smv; a1 += smv;
    }
    {
#pragma unroll
        for (int off = 32; off; off >>= 1) a1 += __shfl_xor(a1, off);
        if (lane == 0) s_red[wid] = a1;
    }
    {
        unsigned sel, sub, top;
        radix_scan(s_hist, lane, kk, sel, sub, top);
        pref = sel << 24; kk -= sub;
    }
    {
        int hb = NW * 256 + wid * 256 + lane * 4;
        s_hist[hb] = 0u; s_hist[hb + 1] = 0u; s_hist[hb + 2] = 0u; s_hist[hb + 3] = 0u;
#pragma unroll
        for (int i = 0; i < EPT; i++) {
            unsigned b = __float_as_uint(ps[i]);
            if ((b & 0xFF000000u) == pref)
                atomicAdd(&s_hist[NW * 256 + wid * 256 + ((b >> 16) & 0xFFu)], 1u);
        }
    }
    __syncthreads();                                   // B3

    // ---- Region B3..B4: fold speech sum; STORE spe (overlaps rounds 1-3); round-1 scan
    float tot1 = (lane < NW) ? s_red[lane] : 0.f;
#pragma unroll
    for (int off = 32; off; off >>= 1) tot1 += __shfl_xor(tot1, off);
    const float spe_scale = speech_budget / fmaxf(tot1, 1e-6f);
#pragma unroll
    for (int c = 0; c < EPT; c++) {
        int t = c * NTH + tid;
        o_spe[t] = v[c] * spe_scale;
    }
    {
        unsigned sel, sub, top;
        radix_scan(s_hist + NW * 256, lane, kk, sel, sub, top);
        pref |= sel << 16; kk -= sub;
    }
    {
        int hb = wid * 256 + lane * 4;
        s_hist[hb] = 0u; s_hist[hb + 1] = 0u; s_hist[hb + 2] = 0u; s_hist[hb + 3] = 0u;
#pragma unroll
        for (int i = 0; i < EPT; i++) {
            unsigned b = __float_as_uint(ps[i]);
            if ((b & 0xFFFF0000u) == pref)
                atomicAdd(&s_hist[wid * 256 + ((b >> 8) & 0xFFu)], 1u);
        }
    }
    __syncthreads();                                   // B4

    // ---- Region B4..B5: round-2 scan; round-3 clear+atomics
    {
        unsigned sel, sub, top;
        radix_scan(s_hist, lane, kk, sel, sub, top);
        pref |= sel << 8; kk -= sub;
    }
    {
        int hb = NW * 256 + wid * 256 + lane * 4;
        s_hist[hb] = 0u; s_hist[hb + 1] = 0u; s_hist[hb + 2] = 0u; s_hist[hb + 3] = 0u;
#pragma unroll
        for (int i = 0; i < EPT; i++) {
            unsigned b = __float_as_uint(ps[i]);
            if ((b & 0xFFFFFF00u) == pref)
                atomicAdd(&s_hist[NW * 256 + wid * 256 + (b & 0xFFu)], 1u);
        }
    }
    __syncthreads();                                   // B5

    // ---- Region B5..B6: round-3 scan; keep top-k; kept-sum partial
    {
        unsigned sel, sub, top;
        radix_scan(s_hist + NW * 256, lane, kk, sel, sub, top);
        pref |= sel; kk -= sub;
        cnt_eq = top - sub;
    }
    const unsigned thr_bits = pref;
    const unsigned keep_eq = kk;

    float accp = 0.f;
    if (cnt_eq == keep_eq) {
#pragma unroll
        for (int c = 0; c < EPT; c++) {
            unsigned b = __float_as_uint(ps[c]);
            float pv = (b >= thr_bits) ? ps[c] : 0.f;
            ps[c] = pv; accp += pv;
        }
    } else {
        unsigned carry_eq = 0u;
#pragma unroll
        for (int c = 0; c < EPT; c++) {
            unsigned b = __float_as_uint(ps[c]);
            bool eq = (b == thr_bits);
            unsigned long long bal = __ballot(eq);
            unsigned lpre = (unsigned)__popcll(bal & ((1ull << lane) - 1ull));
            unsigned wc = (unsigned)__popcll(bal);
            if (lane == 0) s_wu[wid] = wc;
            __syncthreads();
            unsigned woff = 0u, tot = 0u;
#pragma unroll
            for (int w = 0; w < NW; w++) { unsigned x = s_wu[w]; if (w < wid) woff += x; tot += x; }
            __syncthreads();
            unsigned rank = carry_eq + woff + lpre;
            bool keep = (b > thr_bits) || (eq && rank < keep_eq);
            float pv = keep ? ps[c] : 0.f;
            ps[c] = pv; accp += pv;
            carry_eq += tot;
        }
    }
    {
#pragma unroll
        for (int off = 32; off; off >>= 1) accp += __shfl_xor(accp, off);
        if (lane == 0) s_red[wid] = accp;
    }
    __syncthreads();                                   // B6

    // ---- Region B6..B7: fold kept sum; STORE pae+al (overlaps scan); scan prep
    float tot2 = (lane < NW) ? s_red[lane] : 0.f;
#pragma unroll
    for (int off = 32; off; off >>= 1) tot2 += __shfl_xor(tot2, off);
    const float pa_scale = pause_budget / fmaxf(tot2, 1e-6f);
    const float inv_alloc = 1.f / fmaxf(speech_budget + pause_budget, 1e-6f);
#pragma unroll
    for (int c = 0; c < EPT; c++) {
        int t = c * NTH + tid;
        float spe = v[c] * spe_scale;
        float pae = ps[c] * pa_scale;
        o_pae[t] = pae;
        o_al[t] = (spe + pae) * inv_alloc;
        bool in = t < L;
        float x = in ? (spe + pae - durr[c]) : 0.f;
#pragma unroll
        for (int off = 1; off < 64; off <<= 1) {
            float u = __shfl_up(x, off);
            if (lane >= off) x += u;
        }
        durr[c] = x;
        if (lane == 63) s_part[c * NW + wid] = x;
    }
    __syncthreads();                                   // B7 (last barrier)

    // ---- Final: redundant 128-partial scan, then pc/bk stores (32 MB)
    {
        float a = s_part[2 * lane], b = s_part[2 * lane + 1];
        float pair = a + b;
        float inc = pair;
#pragma unroll
        for (int off = 1; off < 64; off <<= 1) {
            float u = __shfl_up(inc, off);
            if (lane >= off) inc += u;
        }
        float excl = inc - pair;
#pragma unroll
        for (int c = 0; c < EPT; c++) {
            int t = c * NTH + tid;
            bool in = t < L;
            int p = c * NW + wid;
            float e  = __shfl(excl, p >> 1);
            float av = __shfl(a,    p >> 1);
            float off0 = e + ((p & 1) ? av : 0.f);
            float incl = off0 + durr[c];
            o_pc[t] = in ? incl : 0.f;
            o_bk[t] = in ? fmaxf(incl, 0.f) : 0.f;
        }
    }

    if (tid == 0) {
        o_sb[row] = speech_budget;
        o_pb[row] = pause_budget;
        o_cf[row] = conf;
    }
}

extern "C" void kernel_launch(void* const* d_in, const int* in_sizes, int n_in,
                              void* d_out, int out_size, void* d_ws, size_t ws_size,
                              hipStream_t stream) {
    const float* dur   = (const float*)d_in[0];
    const float* stats = (const float*)d_in[1];
    const float* trace = (const float*)d_in[2];
    const float* mask  = (const float*)d_in[3];
    const float* cue   = (const float*)d_in[4];
    float* out = (float*)d_out;

    teacher_kernel<<<dim3(BATCH), dim3(NTH), 0, stream>>>(dur, stats, trace, mask, cue, out);
}